// Round 2
// baseline (554.414 us; speedup 1.0000x reference)
//
#include <hip/hip_runtime.h>

#define HH 512
#define WW 512
#define NIMG 12
#define RAD 3

// Fused-2 tile geometry (R2: occupancy fix): output TW x TH, intermediate
// (TW+6) x (TH+6), staged raw (TW+12) x (TH+12). TW=58 makes the
// intermediate width exactly 64 = one wave; TH=16 shrinks LDS to 29.5KB
// so 4 blocks/CU fit (16 waves/CU, VGPR-capped) vs R1's 48.1KB / 3 blocks
// (measured OccupancyPercent 18.6, VALUBusy 55 -> latency-bound).
#define TW 58
#define TH 16
#define IW 64            // TW+6, intermediate cols = wave width
#define IH 22            // TH+6, intermediate rows
#define IW2 72           // padded LDS row stride for intermediate
#define SW 70            // TW+12, stage width (lane tx reads cols tx..tx+6)
#define SH 30            // TH+12=28 needed + 2 pad rows (masked phase-1 rows 22,23 read to 29)
#define GX ((WW + TW - 1) / TW)   // 9 x-tiles (last partial)

typedef float v2 __attribute__((ext_vector_type(2)));

// One side-window-filter iteration over RPW consecutive rows for one wave,
// reading a staged fp32 image+pert pair from LDS and emitting (im',pert')
// per row via the `emit` functor.
//
// NUMERICS CONTRACT (carried from the previous session, R1-R9):
//  - conv = sequential fma over the 7x7 window, (ky,kx) row-major, one
//    accumulator per direction (bit-exact vs the fp32 ref replay).
//  - IM chains feed argmin -> exact per-chain order preserved:
//      * L/R, NW/NE, SW/SE packed as v_pk_fma lanes; each lane's tap
//        sequence identical to the scalar chain.
//      * U/D are SCALAR chains (same tap order). Their (row,row+3) operand
//        pairing can't be register-adjacent; scalar fma reads any register
//        half directly, so 56 fma < 28 pk_fma + ~56 movs.
//  - pi[s][d] holds the pair {row col d, row col d+3}: exactly the operand
//    pair of every packed chain -> zero packing movs.
//  - PERT path: quadrant decomposition identical to R5 (absmax 9.77e-4).
template <int RPW, int LDW, class F>
__device__ __forceinline__ void ring_pass(
    const float* __restrict__ SI, const float* __restrict__ SP,
    int r0, int tx, F emit)
{
    const float w28 = 1.0f / 28.0f;   // fp32-rounded, as in the ref kernels
    const float w16 = 0.0625f;        // exact
    const v2 w28v = {w28, w28};
    const v2 w16v = {w16, w16};

    v2    pi[7][4];   // pi[slot][d] = {row[tx+d], row[tx+d+3]}
    v2    hlr[7];     // pert row partials {hl, hr}
    float cc[7];      // pert center column

    auto rowload = [&](int slot, int m) {
        const float* rI = SI + m * LDW + tx;
        float w0 = rI[0], w1 = rI[1], w2 = rI[2], w3 = rI[3],
              w4 = rI[4], w5 = rI[5], w6 = rI[6];
        pi[slot][0] = (v2){w0, w3};
        pi[slot][1] = (v2){w1, w4};
        pi[slot][2] = (v2){w2, w5};
        pi[slot][3] = (v2){w3, w6};
        const float* rP = SP + m * LDW + tx;
        float b0 = rP[0], b1 = rP[1], b2 = rP[2], b3 = rP[3],
              b4 = rP[4], b5 = rP[5], b6 = rP[6];
        hlr[slot] = (v2){(b0 + b1) + (b2 + b3), (b3 + b4) + (b5 + b6)};
        cc[slot] = b3;
    };

    #pragma unroll
    for (int m = 0; m < 7; ++m)
        rowload(m, r0 + m);

    #pragma unroll
    for (int jj = 0; jj < RPW; ++jj) {
        // ---- im: packed L/R, NW/NE, SW/SE + scalar U, D ----
        v2 aLR = {0.f, 0.f}, aQN = {0.f, 0.f}, aQS = {0.f, 0.f};
        #pragma unroll
        for (int dy = 0; dy < 7; ++dy) {
            const int s = (jj + dy) % 7;
            #pragma unroll
            for (int dx = 0; dx < 4; ++dx)   // L: cols 0..3 | R: cols 3..6
                aLR = __builtin_elementwise_fma(pi[s][dx], w28v, aLR);
        }
        float U = 0.f, Dd = 0.f;
        #pragma unroll
        for (int dy = 0; dy < 4; ++dy) {     // U rows 0..3 | D rows 3..6
            const int su = (jj + dy) % 7;
            const int sd = (jj + dy + 3) % 7;
            // cols 0..6 = pi[0].x pi[1].x pi[2].x pi[3].x pi[1].y pi[2].y pi[3].y
            U = fmaf(pi[su][0].x, w28, U);  U = fmaf(pi[su][1].x, w28, U);
            U = fmaf(pi[su][2].x, w28, U);  U = fmaf(pi[su][3].x, w28, U);
            U = fmaf(pi[su][1].y, w28, U);  U = fmaf(pi[su][2].y, w28, U);
            U = fmaf(pi[su][3].y, w28, U);
            Dd = fmaf(pi[sd][0].x, w28, Dd); Dd = fmaf(pi[sd][1].x, w28, Dd);
            Dd = fmaf(pi[sd][2].x, w28, Dd); Dd = fmaf(pi[sd][3].x, w28, Dd);
            Dd = fmaf(pi[sd][1].y, w28, Dd); Dd = fmaf(pi[sd][2].y, w28, Dd);
            Dd = fmaf(pi[sd][3].y, w28, Dd);
            #pragma unroll
            for (int dx = 0; dx < 4; ++dx) { // NW/NE top rows, SW/SE bottom
                aQN = __builtin_elementwise_fma(pi[su][dx], w16v, aQN);
                aQS = __builtin_elementwise_fma(pi[sd][dx], w16v, aQS);
            }
        }

        const float cI = pi[(jj + 3) % 7][3].x;   // center col 3
        const v2 cI2 = {cI, cI};
        const v2 d01 = aLR - cI2;
        const float d2 = U - cI, d3 = Dd - cI;
        const v2 d45 = aQN - cI2;
        const v2 d67 = aQS - cI2;
        float d[8] = {d01.x, d01.y, d2, d3, d45.x, d45.y, d67.x, d67.y};

        // ---- pert: packed quadrant decomposition (values identical R5) ----
        float e[8];
        const int p0 = (jj + 0) % 7, p1 = (jj + 1) % 7, p2 = (jj + 2) % 7,
                  p3 = (jj + 3) % 7, p4 = (jj + 4) % 7, p5 = (jj + 5) % 7,
                  p6 = (jj + 6) % 7;
        const float cP = cc[p3];
        {
            v2 qN = ((hlr[p0] + hlr[p1]) + (hlr[p2] + hlr[p3])); // (qnw,qne)
            v2 qS = ((hlr[p3] + hlr[p4]) + (hlr[p5] + hlr[p6])); // (qsw,qse)
            float cu = ((cc[p0] + cc[p1]) + (cc[p2] + cc[p3]));
            float cd = ((cc[p3] + cc[p4]) + (cc[p5] + cc[p6]));
            const v2 cP2 = {cP, cP};
            v2 eLR = (qN + qS - hlr[p3]) * w28v - cP2;   // (L, R)
            v2 eQN = qN * w16v - cP2;                    // (NW, NE)
            v2 eQS = qS * w16v - cP2;                    // (SW, SE)
            e[0] = eLR.x;  e[1] = eLR.y;
            e[2] = (qN.x + qN.y - cu) * w28 - cP;        // U
            e[3] = (qS.x + qS.y - cd) * w28 - cP;        // D
            e[4] = eQN.x;  e[5] = eQN.y;
            e[6] = eQS.x;  e[7] = eQS.y;
        }

        // first-index-wins argmin over |d| (jnp.argmin tie-break)
        float bestAbs = fabsf(d[0]);
        float bd = d[0];
        float be = e[0];
        #pragma unroll
        for (int j = 1; j < 8; ++j) {
            float a = fabsf(d[j]);
            bool take = a < bestAbs;
            bestAbs = take ? a : bestAbs;
            bd = take ? d[j] : bd;
            be = take ? e[j] : be;
        }

        emit(jj, cI + bd, cP + be);

        if (jj < RPW - 1)
            rowload(jj % 7, r0 + jj + 7);
    }
}

// Fused 2 iterations per dispatch. Phase 1 computes iteration k for the
// (IH x IW) region into LDS (zeroed outside the image = the ref's
// per-iteration zero padding); phase 2 computes iteration k+1 and stores
// to global. The intermediate passes through fp32 exactly as it previously
// did through global memory -> both iterations bit-identical to unfused.
//
// PERF MODEL (R2): R1 counters showed FETCH/WRITE at ideal, VALUBusy 55%,
// Occupancy 18.6% -> latency-bound at 3 blocks/CU (48KB LDS). Instruction
// floor ~123us total issue; closing the 55->~90% busy gap needs residency.
// TH=16 cuts LDS to 29.5KB -> 4 blocks/CU (VGPR 96 caps at 16 waves/CU),
// at only ~11% more redundant compute per output row.
__global__ __launch_bounds__(256, 4) void swf2(
    const float* __restrict__ im_in, const float* __restrict__ pe_in,
    float* __restrict__ im_out, float* __restrict__ pe_out, int storeIm)
{
    __shared__ float sI0[SH][SW];
    __shared__ float sP0[SH][SW];
    __shared__ float sI1[IH][IW2];
    __shared__ float sP1[IH][IW2];

    const int tid = threadIdx.x;
    const int tx = tid & 63;
    const int wv = tid >> 6;                 // wave id 0..3
    const int x0 = blockIdx.x * TW;
    const int y0 = blockIdx.y * TH;
    const size_t ibase = (size_t)blockIdx.z * (size_t)(HH * WW);
    const float* imb = im_in + ibase;
    const float* peb = pe_in + ibase;

    // Stage raw region [y0-6, y0+24) x [x0-6, x0+64), zero outside image.
    for (int i = tid; i < SH * SW; i += 256) {
        int r = i / SW;
        int c = i - r * SW;
        int gy = y0 - 6 + r;
        int gx = x0 - 6 + c;
        bool ok = ((unsigned)gy < (unsigned)HH) && ((unsigned)gx < (unsigned)WW);
        int gi = gy * WW + gx;
        sI0[r][c] = ok ? imb[gi] : 0.0f;
        sP0[r][c] = ok ? peb[gi] : 0.0f;
    }
    __syncthreads();

    // Phase 1: iteration k over intermediate rows 0..21 (cols = 64 lanes).
    // Single pass: 4 waves x RPW=6 cover rows 0..23; rows 22,23 masked.
    {
        const int base = wv * 6;                       // 0,6,12,18
        ring_pass<6, SW>(&sI0[0][0], &sP0[0][0], base, tx,
            [&](int jj, float vI, float vP) {
                int ir = base + jj;
                if (ir < IH) {
                    int gy = y0 - 3 + ir;
                    int gx = x0 - 3 + tx;
                    bool ok = ((unsigned)gy < (unsigned)HH) &&
                              ((unsigned)gx < (unsigned)WW);
                    sI1[ir][tx] = ok ? vI : 0.0f;   // zero = next-iter padding
                    sP1[ir][tx] = ok ? vP : 0.0f;
                }
            });
    }
    __syncthreads();

    // Phase 2: iteration k+1 over output rows 0..15 (RPW=4, exact cover).
    {
        const int base = wv * 4;                       // 0,4,8,12
        ring_pass<4, IW2>(&sI1[0][0], &sP1[0][0], base, tx,
            [&](int jj, float vI, float vP) {
                int gx = x0 + tx;
                if (tx < TW && gx < WW) {
                    size_t gi = ibase + (size_t)(y0 + base + jj) * WW + gx;
                    if (storeIm) im_out[gi] = vI;
                    pe_out[gi] = vP;
                }
            });
    }
}

extern "C" void kernel_launch(void* const* d_in, const int* in_sizes, int n_in,
                              void* d_out, int out_size, void* d_ws, size_t ws_size,
                              hipStream_t stream) {
    const float* im0 = (const float*)d_in[0];
    const float* pe0 = (const float*)d_in[1];
    float* out = (float*)d_out;

    const size_t npix = (size_t)NIMG * HH * WW;   // 3,145,728
    float* imA = (float*)d_ws;                    // 12.6 MB
    float* imB = imA + npix;                      // 12.6 MB
    float* peB = imB + npix;                      // 12.6 MB (ws total 37.7 MB)
    // pert ping-pongs through d_out: k1 pert->out, k2 reads out writes peB,
    // k3 reads peB writes out. No kernel reads and writes the same buffer.

    dim3 grid(GX, HH / TH, NIMG);                 // 9 x 32 x 12 = 3456 blocks
    dim3 block(256);

    swf2<<<grid, block, 0, stream>>>(im0, pe0, imA, out, 1);  // iters 0-1
    swf2<<<grid, block, 0, stream>>>(imA, out, imB, peB, 1);  // iters 2-3
    swf2<<<grid, block, 0, stream>>>(imB, peB, imA, out, 0);  // iters 4-5
}

// Round 3
// 275.934 us; speedup vs baseline: 2.0092x; 2.0092x over previous
//
#include <hip/hip_runtime.h>

#define HH 512
#define WW 512
#define NIMG 12
#define RAD 3

// Fused-2 tile geometry (R2: occupancy fix, R3: spill fix): output TW x TH,
// intermediate (TW+6) x (TH+6), staged raw (TW+12) x (TH+12). TW=58 makes
// the intermediate width exactly 64 = one wave; TH=16 keeps LDS at 29.5KB.
//
// R3 NOTE (load-bearing): __launch_bounds__ must be plain (256). The R2
// attempt (256,4) clamped the VGPR budget to 64 (< the ~96 the ring state
// needs) -> ring buffers spilled to scratch -> WRITE_SIZE exploded 27MB ->
// 380MB/dispatch and the kernel went memory-bound on spill traffic (554us).
// With plain bounds the compiler uses 96 VGPR (<=128 tier -> 4 waves/EU ->
// 4 blocks/CU anyway, same occupancy target, zero spill).
#define TW 58
#define TH 16
#define IW 64            // TW+6, intermediate cols = wave width
#define IH 22            // TH+6, intermediate rows
#define IW2 72           // padded LDS row stride for intermediate
#define SW 70            // TW+12, stage width (lane tx reads cols tx..tx+6)
#define SH 30            // TH+12=28 needed + 2 pad rows (masked phase-1 rows 22,23 read to 29)
#define GX ((WW + TW - 1) / TW)   // 9 x-tiles (last partial)

typedef float v2 __attribute__((ext_vector_type(2)));

// One side-window-filter iteration over RPW consecutive rows for one wave,
// reading a staged fp32 image+pert pair from LDS and emitting (im',pert')
// per row via the `emit` functor.
//
// NUMERICS CONTRACT (carried from the previous session, R1-R9):
//  - conv = sequential fma over the 7x7 window, (ky,kx) row-major, one
//    accumulator per direction (bit-exact vs the fp32 ref replay).
//  - IM chains feed argmin -> exact per-chain order preserved:
//      * L/R, NW/NE, SW/SE packed as v_pk_fma lanes; each lane's tap
//        sequence identical to the scalar chain.
//      * U/D are SCALAR chains (same tap order). Their (row,row+3) operand
//        pairing can't be register-adjacent; scalar fma reads any register
//        half directly, so 56 fma < 28 pk_fma + ~56 movs.
//  - pi[s][d] holds the pair {row col d, row col d+3}: exactly the operand
//    pair of every packed chain -> zero packing movs.
//  - PERT path: quadrant decomposition identical to R5 (absmax 9.77e-4).
template <int RPW, int LDW, class F>
__device__ __forceinline__ void ring_pass(
    const float* __restrict__ SI, const float* __restrict__ SP,
    int r0, int tx, F emit)
{
    const float w28 = 1.0f / 28.0f;   // fp32-rounded, as in the ref kernels
    const float w16 = 0.0625f;        // exact
    const v2 w28v = {w28, w28};
    const v2 w16v = {w16, w16};

    v2    pi[7][4];   // pi[slot][d] = {row[tx+d], row[tx+d+3]}
    v2    hlr[7];     // pert row partials {hl, hr}
    float cc[7];      // pert center column

    auto rowload = [&](int slot, int m) {
        const float* rI = SI + m * LDW + tx;
        float w0 = rI[0], w1 = rI[1], w2 = rI[2], w3 = rI[3],
              w4 = rI[4], w5 = rI[5], w6 = rI[6];
        pi[slot][0] = (v2){w0, w3};
        pi[slot][1] = (v2){w1, w4};
        pi[slot][2] = (v2){w2, w5};
        pi[slot][3] = (v2){w3, w6};
        const float* rP = SP + m * LDW + tx;
        float b0 = rP[0], b1 = rP[1], b2 = rP[2], b3 = rP[3],
              b4 = rP[4], b5 = rP[5], b6 = rP[6];
        hlr[slot] = (v2){(b0 + b1) + (b2 + b3), (b3 + b4) + (b5 + b6)};
        cc[slot] = b3;
    };

    #pragma unroll
    for (int m = 0; m < 7; ++m)
        rowload(m, r0 + m);

    #pragma unroll
    for (int jj = 0; jj < RPW; ++jj) {
        // ---- im: packed L/R, NW/NE, SW/SE + scalar U, D ----
        v2 aLR = {0.f, 0.f}, aQN = {0.f, 0.f}, aQS = {0.f, 0.f};
        #pragma unroll
        for (int dy = 0; dy < 7; ++dy) {
            const int s = (jj + dy) % 7;
            #pragma unroll
            for (int dx = 0; dx < 4; ++dx)   // L: cols 0..3 | R: cols 3..6
                aLR = __builtin_elementwise_fma(pi[s][dx], w28v, aLR);
        }
        float U = 0.f, Dd = 0.f;
        #pragma unroll
        for (int dy = 0; dy < 4; ++dy) {     // U rows 0..3 | D rows 3..6
            const int su = (jj + dy) % 7;
            const int sd = (jj + dy + 3) % 7;
            // cols 0..6 = pi[0].x pi[1].x pi[2].x pi[3].x pi[1].y pi[2].y pi[3].y
            U = fmaf(pi[su][0].x, w28, U);  U = fmaf(pi[su][1].x, w28, U);
            U = fmaf(pi[su][2].x, w28, U);  U = fmaf(pi[su][3].x, w28, U);
            U = fmaf(pi[su][1].y, w28, U);  U = fmaf(pi[su][2].y, w28, U);
            U = fmaf(pi[su][3].y, w28, U);
            Dd = fmaf(pi[sd][0].x, w28, Dd); Dd = fmaf(pi[sd][1].x, w28, Dd);
            Dd = fmaf(pi[sd][2].x, w28, Dd); Dd = fmaf(pi[sd][3].x, w28, Dd);
            Dd = fmaf(pi[sd][1].y, w28, Dd); Dd = fmaf(pi[sd][2].y, w28, Dd);
            Dd = fmaf(pi[sd][3].y, w28, Dd);
            #pragma unroll
            for (int dx = 0; dx < 4; ++dx) { // NW/NE top rows, SW/SE bottom
                aQN = __builtin_elementwise_fma(pi[su][dx], w16v, aQN);
                aQS = __builtin_elementwise_fma(pi[sd][dx], w16v, aQS);
            }
        }

        const float cI = pi[(jj + 3) % 7][3].x;   // center col 3
        const v2 cI2 = {cI, cI};
        const v2 d01 = aLR - cI2;
        const float d2 = U - cI, d3 = Dd - cI;
        const v2 d45 = aQN - cI2;
        const v2 d67 = aQS - cI2;
        float d[8] = {d01.x, d01.y, d2, d3, d45.x, d45.y, d67.x, d67.y};

        // ---- pert: packed quadrant decomposition (values identical R5) ----
        float e[8];
        const int p0 = (jj + 0) % 7, p1 = (jj + 1) % 7, p2 = (jj + 2) % 7,
                  p3 = (jj + 3) % 7, p4 = (jj + 4) % 7, p5 = (jj + 5) % 7,
                  p6 = (jj + 6) % 7;
        const float cP = cc[p3];
        {
            v2 qN = ((hlr[p0] + hlr[p1]) + (hlr[p2] + hlr[p3])); // (qnw,qne)
            v2 qS = ((hlr[p3] + hlr[p4]) + (hlr[p5] + hlr[p6])); // (qsw,qse)
            float cu = ((cc[p0] + cc[p1]) + (cc[p2] + cc[p3]));
            float cd = ((cc[p3] + cc[p4]) + (cc[p5] + cc[p6]));
            const v2 cP2 = {cP, cP};
            v2 eLR = (qN + qS - hlr[p3]) * w28v - cP2;   // (L, R)
            v2 eQN = qN * w16v - cP2;                    // (NW, NE)
            v2 eQS = qS * w16v - cP2;                    // (SW, SE)
            e[0] = eLR.x;  e[1] = eLR.y;
            e[2] = (qN.x + qN.y - cu) * w28 - cP;        // U
            e[3] = (qS.x + qS.y - cd) * w28 - cP;        // D
            e[4] = eQN.x;  e[5] = eQN.y;
            e[6] = eQS.x;  e[7] = eQS.y;
        }

        // first-index-wins argmin over |d| (jnp.argmin tie-break)
        float bestAbs = fabsf(d[0]);
        float bd = d[0];
        float be = e[0];
        #pragma unroll
        for (int j = 1; j < 8; ++j) {
            float a = fabsf(d[j]);
            bool take = a < bestAbs;
            bestAbs = take ? a : bestAbs;
            bd = take ? d[j] : bd;
            be = take ? e[j] : be;
        }

        emit(jj, cI + bd, cP + be);

        if (jj < RPW - 1)
            rowload(jj % 7, r0 + jj + 7);
    }
}

// Fused 2 iterations per dispatch. Phase 1 computes iteration k for the
// (IH x IW) region into LDS (zeroed outside the image = the ref's
// per-iteration zero padding); phase 2 computes iteration k+1 and stores
// to global. The intermediate passes through fp32 exactly as it previously
// did through global memory -> both iterations bit-identical to unfused.
//
// PERF MODEL (R3): R1 showed latency-bound at 3 blocks/CU (48KB LDS,
// VALUBusy 55, Occ 18.6). R2's TH=16 geometry raised occupancy to ~40%
// but its launch_bounds(256,4) clamped VGPR to 64 -> scratch spill ->
// 380MB writes/dispatch. R3 = TH=16 geometry + plain bounds (VGPR 96,
// no spill): R2's residency with R1's clean VALU profile.
__global__ __launch_bounds__(256) void swf2(
    const float* __restrict__ im_in, const float* __restrict__ pe_in,
    float* __restrict__ im_out, float* __restrict__ pe_out, int storeIm)
{
    __shared__ float sI0[SH][SW];
    __shared__ float sP0[SH][SW];
    __shared__ float sI1[IH][IW2];
    __shared__ float sP1[IH][IW2];

    const int tid = threadIdx.x;
    const int tx = tid & 63;
    const int wv = tid >> 6;                 // wave id 0..3
    const int x0 = blockIdx.x * TW;
    const int y0 = blockIdx.y * TH;
    const size_t ibase = (size_t)blockIdx.z * (size_t)(HH * WW);
    const float* imb = im_in + ibase;
    const float* peb = pe_in + ibase;

    // Stage raw region [y0-6, y0+24) x [x0-6, x0+64), zero outside image.
    for (int i = tid; i < SH * SW; i += 256) {
        int r = i / SW;
        int c = i - r * SW;
        int gy = y0 - 6 + r;
        int gx = x0 - 6 + c;
        bool ok = ((unsigned)gy < (unsigned)HH) && ((unsigned)gx < (unsigned)WW);
        int gi = gy * WW + gx;
        sI0[r][c] = ok ? imb[gi] : 0.0f;
        sP0[r][c] = ok ? peb[gi] : 0.0f;
    }
    __syncthreads();

    // Phase 1: iteration k over intermediate rows 0..21 (cols = 64 lanes).
    // Single pass: 4 waves x RPW=6 cover rows 0..23; rows 22,23 masked.
    {
        const int base = wv * 6;                       // 0,6,12,18
        ring_pass<6, SW>(&sI0[0][0], &sP0[0][0], base, tx,
            [&](int jj, float vI, float vP) {
                int ir = base + jj;
                if (ir < IH) {
                    int gy = y0 - 3 + ir;
                    int gx = x0 - 3 + tx;
                    bool ok = ((unsigned)gy < (unsigned)HH) &&
                              ((unsigned)gx < (unsigned)WW);
                    sI1[ir][tx] = ok ? vI : 0.0f;   // zero = next-iter padding
                    sP1[ir][tx] = ok ? vP : 0.0f;
                }
            });
    }
    __syncthreads();

    // Phase 2: iteration k+1 over output rows 0..15 (RPW=4, exact cover).
    {
        const int base = wv * 4;                       // 0,4,8,12
        ring_pass<4, IW2>(&sI1[0][0], &sP1[0][0], base, tx,
            [&](int jj, float vI, float vP) {
                int gx = x0 + tx;
                if (tx < TW && gx < WW) {
                    size_t gi = ibase + (size_t)(y0 + base + jj) * WW + gx;
                    if (storeIm) im_out[gi] = vI;
                    pe_out[gi] = vP;
                }
            });
    }
}

extern "C" void kernel_launch(void* const* d_in, const int* in_sizes, int n_in,
                              void* d_out, int out_size, void* d_ws, size_t ws_size,
                              hipStream_t stream) {
    const float* im0 = (const float*)d_in[0];
    const float* pe0 = (const float*)d_in[1];
    float* out = (float*)d_out;

    const size_t npix = (size_t)NIMG * HH * WW;   // 3,145,728
    float* imA = (float*)d_ws;                    // 12.6 MB
    float* imB = imA + npix;                      // 12.6 MB
    float* peB = imB + npix;                      // 12.6 MB (ws total 37.7 MB)
    // pert ping-pongs through d_out: k1 pert->out, k2 reads out writes peB,
    // k3 reads peB writes out. No kernel reads and writes the same buffer.

    dim3 grid(GX, HH / TH, NIMG);                 // 9 x 32 x 12 = 3456 blocks
    dim3 block(256);

    swf2<<<grid, block, 0, stream>>>(im0, pe0, imA, out, 1);  // iters 0-1
    swf2<<<grid, block, 0, stream>>>(imA, out, imB, peB, 1);  // iters 2-3
    swf2<<<grid, block, 0, stream>>>(imB, peB, imA, out, 0);  // iters 4-5
}

// Round 4
// 225.505 us; speedup vs baseline: 2.4585x; 1.2236x over previous
//
#include <hip/hip_runtime.h>

#define HH 512
#define WW 512
#define NIMG 12
#define RAD 3
#define TW 64
#define TH 16
#define LW (TW + 2*RAD)   // 70
#define LH (TH + 2*RAD)   // 22
#define RPW 4             // output rows per wave (TH / 4 waves)

typedef float v2 __attribute__((ext_vector_type(2)));

// R4: unfused 6-dispatch structure (the proven 235us shape: TW=64 tiles =
// exactly one wave wide, no hot-loop masks, 12.3KB LDS, one barrier) with
// the pi-pair inner loop validated in the R1/R3 fused kernels.
//
// SESSION LEDGER:
//  R1 fuse2 (48KB LDS): 256us. Occ 18.6, busy 55 -> latency-bound.
//  R2 fuse2 + launch_bounds(256,4): 554us. VGPR clamp 64 -> scratch spill
//     (WRITE 380MB/disp). 2nd arg of launch_bounds is a VGPR clamp first.
//  R3 fuse2 TH=16 (29.7KB): 276us. Occ 20.6 (VGPR tier pins 4 waves/SIMD
//     regardless of LDS), issue = R1 + 11% redundancy. Fusion arc is a
//     net loss: the "fixed ~20us" was structure-scaling stall, not launch.
//  R4: keep the only real win from R1-R3 -- the operand layout.
//
// NUMERICS CONTRACT (unchanged; harness-validated R1/R3, absmax 9.77e-4):
//  - conv = sequential fma over the 7x7 window, (ky,kx) row-major, one
//    accumulator per direction (bit-exact im path vs the fp32 ref replay).
//  - L/R, NW/NE, SW/SE packed as v_pk_fma lanes; each lane's tap sequence
//    identical to the scalar chain. U/D scalar chains, same tap order
//    (their (row,row+3) pairing can't be register-adjacent; 56 scalar fma
//    < 28 pk_fma + ~56 movs).
//  - pi[s][d] = {row[tx+d], row[tx+d+3]}: exactly the operand pair of
//    every packed chain -> zero packing movs (the old baseline rebuilt
//    stride-3 pairs per fma, ~110 v_movs/px).
//  - PERT: quadrant decomposition identical to R5 of the prior session.
template <int NR, int LDW, class F>
__device__ __forceinline__ void ring_pass(
    const float* __restrict__ SI, const float* __restrict__ SP,
    int r0, int tx, F emit)
{
    const float w28 = 1.0f / 28.0f;   // fp32-rounded, as in the ref kernels
    const float w16 = 0.0625f;        // exact
    const v2 w28v = {w28, w28};
    const v2 w16v = {w16, w16};

    v2    pi[7][4];   // pi[slot][d] = {row[tx+d], row[tx+d+3]}
    v2    hlr[7];     // pert row partials {hl, hr}
    float cc[7];      // pert center column

    auto rowload = [&](int slot, int m) {
        const float* rI = SI + m * LDW + tx;
        float w0 = rI[0], w1 = rI[1], w2 = rI[2], w3 = rI[3],
              w4 = rI[4], w5 = rI[5], w6 = rI[6];
        pi[slot][0] = (v2){w0, w3};
        pi[slot][1] = (v2){w1, w4};
        pi[slot][2] = (v2){w2, w5};
        pi[slot][3] = (v2){w3, w6};
        const float* rP = SP + m * LDW + tx;
        float b0 = rP[0], b1 = rP[1], b2 = rP[2], b3 = rP[3],
              b4 = rP[4], b5 = rP[5], b6 = rP[6];
        hlr[slot] = (v2){(b0 + b1) + (b2 + b3), (b3 + b4) + (b5 + b6)};
        cc[slot] = b3;
    };

    #pragma unroll
    for (int m = 0; m < 7; ++m)
        rowload(m, r0 + m);

    #pragma unroll
    for (int jj = 0; jj < NR; ++jj) {
        // ---- im: packed L/R, NW/NE, SW/SE + scalar U, D ----
        v2 aLR = {0.f, 0.f}, aQN = {0.f, 0.f}, aQS = {0.f, 0.f};
        #pragma unroll
        for (int dy = 0; dy < 7; ++dy) {
            const int s = (jj + dy) % 7;
            #pragma unroll
            for (int dx = 0; dx < 4; ++dx)   // L: cols 0..3 | R: cols 3..6
                aLR = __builtin_elementwise_fma(pi[s][dx], w28v, aLR);
        }
        float U = 0.f, Dd = 0.f;
        #pragma unroll
        for (int dy = 0; dy < 4; ++dy) {     // U rows 0..3 | D rows 3..6
            const int su = (jj + dy) % 7;
            const int sd = (jj + dy + 3) % 7;
            // cols 0..6 = pi[0].x pi[1].x pi[2].x pi[3].x pi[1].y pi[2].y pi[3].y
            U = fmaf(pi[su][0].x, w28, U);  U = fmaf(pi[su][1].x, w28, U);
            U = fmaf(pi[su][2].x, w28, U);  U = fmaf(pi[su][3].x, w28, U);
            U = fmaf(pi[su][1].y, w28, U);  U = fmaf(pi[su][2].y, w28, U);
            U = fmaf(pi[su][3].y, w28, U);
            Dd = fmaf(pi[sd][0].x, w28, Dd); Dd = fmaf(pi[sd][1].x, w28, Dd);
            Dd = fmaf(pi[sd][2].x, w28, Dd); Dd = fmaf(pi[sd][3].x, w28, Dd);
            Dd = fmaf(pi[sd][1].y, w28, Dd); Dd = fmaf(pi[sd][2].y, w28, Dd);
            Dd = fmaf(pi[sd][3].y, w28, Dd);
            #pragma unroll
            for (int dx = 0; dx < 4; ++dx) { // NW/NE top rows, SW/SE bottom
                aQN = __builtin_elementwise_fma(pi[su][dx], w16v, aQN);
                aQS = __builtin_elementwise_fma(pi[sd][dx], w16v, aQS);
            }
        }

        const float cI = pi[(jj + 3) % 7][3].x;   // center col 3
        const v2 cI2 = {cI, cI};
        const v2 d01 = aLR - cI2;
        const float d2 = U - cI, d3 = Dd - cI;
        const v2 d45 = aQN - cI2;
        const v2 d67 = aQS - cI2;
        float d[8] = {d01.x, d01.y, d2, d3, d45.x, d45.y, d67.x, d67.y};

        // ---- pert: packed quadrant decomposition (values identical R5) ----
        float e[8];
        const int p0 = (jj + 0) % 7, p1 = (jj + 1) % 7, p2 = (jj + 2) % 7,
                  p3 = (jj + 3) % 7, p4 = (jj + 4) % 7, p5 = (jj + 5) % 7,
                  p6 = (jj + 6) % 7;
        const float cP = cc[p3];
        {
            v2 qN = ((hlr[p0] + hlr[p1]) + (hlr[p2] + hlr[p3])); // (qnw,qne)
            v2 qS = ((hlr[p3] + hlr[p4]) + (hlr[p5] + hlr[p6])); // (qsw,qse)
            float cu = ((cc[p0] + cc[p1]) + (cc[p2] + cc[p3]));
            float cd = ((cc[p3] + cc[p4]) + (cc[p5] + cc[p6]));
            const v2 cP2 = {cP, cP};
            v2 eLR = (qN + qS - hlr[p3]) * w28v - cP2;   // (L, R)
            v2 eQN = qN * w16v - cP2;                    // (NW, NE)
            v2 eQS = qS * w16v - cP2;                    // (SW, SE)
            e[0] = eLR.x;  e[1] = eLR.y;
            e[2] = (qN.x + qN.y - cu) * w28 - cP;        // U
            e[3] = (qS.x + qS.y - cd) * w28 - cP;        // D
            e[4] = eQN.x;  e[5] = eQN.y;
            e[6] = eQS.x;  e[7] = eQS.y;
        }

        // first-index-wins argmin over |d| (jnp.argmin tie-break)
        float bestAbs = fabsf(d[0]);
        float bd = d[0];
        float be = e[0];
        #pragma unroll
        for (int j = 1; j < 8; ++j) {
            float a = fabsf(d[j]);
            bool take = a < bestAbs;
            bestAbs = take ? a : bestAbs;
            bd = take ? d[j] : bd;
            be = take ? e[j] : be;
        }

        emit(jj, cI + bd, cP + be);

        if (jj < NR - 1)
            rowload(jj % 7, r0 + jj + 7);
    }
}

// One side-window-filter iteration. Launch shape 256-thr / 3072-block is
// load-bearing (prior session: one-wave blocks destroyed cache locality,
// FETCH 23->219MB). TW=64 => every lane/row valid, no hot-loop masks.
__global__ __launch_bounds__(256) void swf_step(
    const float* __restrict__ im_in, const float* __restrict__ pe_in,
    float* __restrict__ im_out, float* __restrict__ pe_out, int storeIm)
{
    __shared__ float sI[LH][LW];
    __shared__ float sP[LH][LW];

    const int tid = threadIdx.x;
    const int tx = tid & 63;
    const int wv = tid >> 6;          // wave id 0..3
    const int x0 = blockIdx.x * TW;
    const int y0 = blockIdx.y * TH;
    const size_t base = (size_t)blockIdx.z * (size_t)(HH * WW);
    const float* imb = im_in + base;
    const float* peb = pe_in + base;

    // Stage raw tile + halo(3) into LDS, zero padding outside the image
    for (int i = tid; i < LH * LW; i += 256) {
        int r = i / LW;
        int c = i - r * LW;
        int gy = y0 - RAD + r;
        int gx = x0 - RAD + c;
        bool ok = ((unsigned)gy < (unsigned)HH) && ((unsigned)gx < (unsigned)WW);
        int gi = gy * WW + gx;
        sI[r][c] = ok ? imb[gi] : 0.0f;
        sP[r][c] = ok ? peb[gi] : 0.0f;
    }
    __syncthreads();

    const int r0 = wv * RPW;          // wave's slab: sI rows r0 .. r0+RPW+5
    ring_pass<RPW, LW>(&sI[0][0], &sP[0][0], r0, tx,
        [&](int jj, float vI, float vP) {
            const size_t gi = base + (size_t)(y0 + r0 + jj) * WW + (x0 + tx);
            if (storeIm) im_out[gi] = vI;
            pe_out[gi] = vP;
        });
}

extern "C" void kernel_launch(void* const* d_in, const int* in_sizes, int n_in,
                              void* d_out, int out_size, void* d_ws, size_t ws_size,
                              hipStream_t stream) {
    const float* im0 = (const float*)d_in[0];
    const float* pe0 = (const float*)d_in[1];
    float* out = (float*)d_out;

    const size_t npix = (size_t)NIMG * HH * WW;   // 3,145,728
    float* imA = (float*)d_ws;                    // 12.6 MB
    float* imB = imA + npix;                      // 12.6 MB
    float* peA = imB + npix;                      // 12.6 MB (ws total 37.7 MB)
    float* peB = out;  // d_out doubles as the second pert buffer; parity
                       // lands the final (iter-5) pert write in d_out.

    dim3 grid(WW / TW, HH / TH, NIMG);            // 8 x 32 x 12 = 3072 blocks
    dim3 block(256);

    swf_step<<<grid, block, 0, stream>>>(im0, pe0, imA, peA, 1);  // iter 0
    swf_step<<<grid, block, 0, stream>>>(imA, peA, imB, peB, 1);  // iter 1
    swf_step<<<grid, block, 0, stream>>>(imB, peB, imA, peA, 1);  // iter 2
    swf_step<<<grid, block, 0, stream>>>(imA, peA, imB, peB, 1);  // iter 3
    swf_step<<<grid, block, 0, stream>>>(imB, peB, imA, peA, 1);  // iter 4
    // iter 5: im output is dead (result = filtered pert only) -> skip store
    swf_step<<<grid, block, 0, stream>>>(imA, peA, imB, out, 0);  // iter 5
}